// Round 1
// baseline (9280.884 us; speedup 1.0000x reference)
//
#include <hip/hip_runtime.h>
#include <cmath>

#define T_STEPS 128
#define B_SZ    4
#define L_DIM   6368
#define L4V     1592      // L_DIM/4
#define KH      3184      // float4 slots of theta staged per half
#define KH4     796       // A-row float4s per half (796 = 12*64 + 28)
#define H1_DIM  2133
#define H2_DIM  4250
#define NBLK    512
#define NMV     511
#define NPAIR   3184      // L_DIM/2 row-pairs

// ws layout (float offsets)
#define OFF_THA  0
#define OFF_THB  25472
#define OFF_W1T  50944     // 2 slots * 16384
#define OFF_W2T  83712     // 2 slots * 8192
#define OFF_DIFF 100096    // 2 slots * 68
#define OFF_H1   100236    // 4*2133 scratch (init only)
#define OFF_H2   108768    // 4*4250 scratch (init only; ends 125768)
#define OFF_CTR  125824    // barrier: 17 slots * 32-u32 stride (zero 576 words)

__device__ inline void fma4(float4& acc, float4 a, float4 t0, float4 t1, float4 t2, float4 t3) {
    acc.x += a.x*t0.x + a.y*t1.x + a.z*t2.x + a.w*t3.x;
    acc.y += a.x*t0.y + a.y*t1.y + a.z*t2.y + a.w*t3.y;
    acc.z += a.x*t0.z + a.y*t1.z + a.z*t2.z + a.w*t3.z;
    acc.w += a.x*t0.w + a.y*t1.w + a.z*t2.w + a.w*t3.w;
}

__device__ inline float4 red4(float4 v) {
    #pragma unroll
    for (int off = 32; off; off >>= 1) {
        v.x += __shfl_xor(v.x, off);
        v.y += __shfl_xor(v.y, off);
        v.z += __shfl_xor(v.z, off);
        v.w += __shfl_xor(v.w, off);
    }
    return v;
}

__device__ inline float4 bminit(const float* __restrict__ Bm, const float* __restrict__ dvec,
                                int r, int l) {
    float4 a = make_float4(0.f, 0.f, 0.f, 0.f);
    if (l < 17) {
        float bv = Bm[r*17 + l];
        a.x = bv * dvec[l];
        a.y = bv * dvec[17 + l];
        a.z = bv * dvec[34 + l];
        a.w = bv * dvec[51 + l];
    }
    return a;
}

// scatter w1/w2 regions of theta' transposed for the root MLP's coalesced reads
__device__ inline void aux_write(float4* w1o, float4* w2o, int r, float4 v) {
    if (r >= 128 && r < 4224) {
        int j = r - 128;                   // j = r_mlp*64 + k
        w1o[(j & 63)*64 + (j >> 6)] = v;   // [k][r_mlp] x 4 batches
    } else if (r >= 4288 && r < 6336) {
        int j = r - 4288;
        w2o[(j & 63)*32 + (j >> 6)] = v;
    }
}

__device__ inline float softplusf(float x) {
    return (x > 20.f) ? x : log1pf(expf(x));
}

// Grid barrier, iteration it1 = it+1 (1-based).
// ctr slots (stride 32 u32 = one 128B line each):
//   [0..7]  : arrival counters (block group = blk & 7, 64 blocks each)
//   [8]     : level-2 counter (one inc per group per iteration)
//   [9..16] : release flags, replicated x8 (value = completed iteration count)
// All counter ops are relaxed RMWs -> execute at the coherence point, never stale,
// and polls do NOT emit buffer_inv (unlike acquire loads). Data coherence comes
// from exactly one release fence before arrival and one acquire fence after wake.
__device__ inline void grid_barrier(unsigned* ctr, int myc, unsigned it1) {
    __syncthreads();   // all waves drain their vmem (waitcnt) before signaling
    if (threadIdx.x == 0) {
        __threadfence();  // release: write back our theta'/w1t/w2t/diff stores
        unsigned old = __hip_atomic_fetch_add(&ctr[myc*32], 1u,
                           __ATOMIC_RELAXED, __HIP_MEMORY_SCOPE_AGENT);
        if (old == it1*64u - 1u) {          // last arriver of my group
            unsigned o2 = __hip_atomic_fetch_add(&ctr[8*32], 1u,
                              __ATOMIC_RELAXED, __HIP_MEMORY_SCOPE_AGENT);
            if (o2 == it1*8u - 1u) {        // last group: release everyone
                #pragma unroll
                for (int c = 0; c < 8; ++c)
                    __hip_atomic_fetch_add(&ctr[(9 + c)*32], 1u,
                        __ATOMIC_RELAXED, __HIP_MEMORY_SCOPE_AGENT);
            }
        }
        while (__hip_atomic_fetch_add(&ctr[(9 + myc)*32], 0u,
                   __ATOMIC_RELAXED, __HIP_MEMORY_SCOPE_AGENT) < it1)
            __builtin_amdgcn_s_sleep(4);
        __threadfence();  // acquire: invalidate L1/L2 before reading others' writes
    }
    __syncthreads();
}

// One matvec trip: 2 A-row float4 loads + 4 swizzled LDS reads + 32 FMAs
#define MV_TRIP(JJ)                                                   \
    {                                                                 \
        const int j_ = (JJ);                                          \
        float4 av0 = a0[j_], av1 = a1[j_];                            \
        const int sw_ = (j_ >> 1) & 7;                                \
        float4 t0 = sth[(4*j_ + 0) ^ sw_];                            \
        float4 t1 = sth[(4*j_ + 1) ^ sw_];                            \
        float4 t2 = sth[(4*j_ + 2) ^ sw_];                            \
        float4 t3 = sth[(4*j_ + 3) ^ sw_];                            \
        fma4(acc0, av0, t0, t1, t2, t3);                              \
        fma4(acc1, av1, t0, t1, t2, t3);                              \
    }

__global__ __launch_bounds__(512, 4)   // VGPR<=128 -> >=2 blocks/CU -> 512 blocks resident
void seq_kernel(const float* __restrict__ A,
                const float* __restrict__ Bm,
                const float* __restrict__ xs,
                const float* __restrict__ ts,
                float* __restrict__ outp,
                float* thetaA, float* thetaB,
                float* w1t, float* w2t, float* diffb,
                unsigned* ctr)
{
    __shared__ float4 sth[KH];      // 50944 B; XOR-swizzled: logical s at phys s^((s>>3)&7)
    const int blk = blockIdx.x;
    const int tid = threadIdx.x;
    const int w = tid >> 6, l = tid & 63;
    const int myc = blk & 7;
    const float4* A4 = (const float4*)A;

    if (blk < NMV) {
        // --------- matvec blocks: one row-pair per wave ---------
        const int p0 = (blk * NPAIR) / NMV;
        const int p1 = ((blk + 1) * NPAIR) / NMV;   // 6..7 pairs per block (<=8 waves)
        const int pA = p0 + w;
        const bool act = pA < p1;
        const int rA = pA * 2;

        for (int it = 0; it < T_STEPS; ++it) {
            const float4* thIn4 = (const float4*)((it & 1) ? thetaB : thetaA);
            float4* thOut4 = (float4*)((it & 1) ? thetaA : thetaB);
            float4* w1o = (float4*)(w1t + ((it + 1) & 1) * 16384);
            float4* w2o = (float4*)(w2t + ((it + 1) & 1) * 8192);
            const float* dvec = diffb + (it & 1) * 68;

            float4 acc0 = bminit(Bm, dvec, rA,     l);
            float4 acc1 = bminit(Bm, dvec, rA + 1, l);

            for (int h = 0; h < 2; ++h) {
                __syncthreads();  // protect LDS from previous half / iteration
                // swizzled stage: conflict-free ds_write (each 8-lane group covers all banks)
                for (int s = tid; s < KH; s += 512)
                    sth[s ^ ((s >> 3) & 7)] = thIn4[h*KH + s];
                __syncthreads();
                if (act) {
                    const float4* a0 = A4 + (size_t)rA * L4V + h*KH4;
                    const float4* a1 = a0 + L4V;
                    #pragma unroll
                    for (int m = 0; m < 12; ++m)       // compile-time trips -> deep pipelining
                        MV_TRIP(l + m*64)
                    if (l < 28)                        // 796 = 12*64 + 28 tail
                        MV_TRIP(l + 768)
                }
            }
            if (act) {
                acc0 = red4(acc0); acc1 = red4(acc1);
                if (l == 0) {
                    thOut4[rA]     = acc0;  aux_write(w1o, w2o, rA,     acc0);
                    thOut4[rA + 1] = acc1;  aux_write(w1o, w2o, rA + 1, acc1);
                }
            }
            grid_barrier(ctr, myc, (unsigned)(it + 1));
        }
    } else {
        // --------- root block: root_apply_{it-1} + prepare diff_{it+1} ---------
        const int b = w;  // waves 0..3 = batches; 4..7 idle
        for (int it = 0; it <= T_STEPS; ++it) {
            float xv = 0.f;
            if (b < B_SZ) {
                if (it >= 1) {
                    const int t = it - 1;
                    const float* th  = (it & 1) ? thetaB : thetaA;  // theta^{it}
                    const float* w1c = w1t + (it & 1) * 16384;
                    const float* w2c = w2t + (it & 1) * 8192;
                    float tcur = ts[b*T_STEPS + t];
                    float tin = (t >= 1) ? (2.f*tcur - ts[b*T_STEPS + t - 1]) : tcur;
                    // h0 = relu(w0*tin + c0)
                    float h0 = fmaxf(th[l*4 + b] * tin + th[(64 + l)*4 + b], 0.f);
                    // h1 = relu(w1 @ h0 + c1)
                    float a1v = th[(4224 + l)*4 + b];
                    #pragma unroll
                    for (int k = 0; k < 64; ++k)
                        a1v += w1c[(k*64 + l)*4 + b] * __shfl(h0, k);
                    float h1 = fmaxf(a1v, 0.f);
                    // o = w2 @ h1 + c2  (32 outputs, lanes 0..31)
                    float ov = th[(6336 + (l & 31))*4 + b];
                    #pragma unroll
                    for (int k = 0; k < 64; ++k)
                        ov += w2c[(k*32 + (l & 31))*4 + b] * __shfl(h1, k);
                    if (l < 32) {
                        xv = (l < 16) ? tanhf(ov) : softplusf(ov);
                        outp[(b*T_STEPS + t)*32 + l] = xv;
                    }
                }
                if (it + 1 <= T_STEPS - 1) {
                    float* dd = diffb + ((it + 1) & 1) * 68 + b*17;
                    if (l < 16) {
                        float xprev = (it >= 1) ? xv : xs[(size_t)(b*T_STEPS)*16 + l];
                        dd[1 + l] = xs[(size_t)(b*T_STEPS + it + 1)*16 + l] - xprev;
                    } else if (l == 16) {
                        dd[0] = ts[b*T_STEPS + it + 1] - ts[b*T_STEPS + it];
                    }
                }
            }
            if (it < T_STEPS) grid_barrier(ctr, myc, (unsigned)(it + 1));
        }
    }
}

// h1 = relu(W1 @ xs0 + b1), plus zero diff slots and barrier counters
__global__ __launch_bounds__(256)
void init_h1(const float* __restrict__ xs, const float* __restrict__ W1,
             const float* __restrict__ b1, float* __restrict__ h1ws,
             float* __restrict__ diffb, unsigned* __restrict__ ctr)
{
    const int b = blockIdx.y;
    const int r = blockIdx.x * 256 + threadIdx.x;
    if (blockIdx.x == 0 && b == 0) {
        if (threadIdx.x < 136) diffb[threadIdx.x] = 0.f;
        for (int z = threadIdx.x; z < 576; z += 256) ctr[z] = 0u;
    }
    if (r < H1_DIM) {
        const float* wr = W1 + r*16;
        const float* x0 = xs + (size_t)b * T_STEPS * 16;
        float s = b1[r];
        #pragma unroll
        for (int k = 0; k < 16; ++k) s += wr[k] * x0[k];
        h1ws[b*H1_DIM + r] = fmaxf(s, 0.f);
    }
}

// out[b][r] = maybe_relu(sum_k W[r][k]*in[b][k] + bias[r]); ilv => out[r*4+b]
__global__ __launch_bounds__(256)
void init_mm(const float* __restrict__ W, const float* __restrict__ bias,
             const float* __restrict__ in, float* __restrict__ outp,
             int rows, int K, int dorelu, int ilv)
{
    const int w = threadIdx.x >> 6, l = threadIdx.x & 63;
    const int gw = blockIdx.x * 4 + w;
    const int nw = gridDim.x * 4;
    for (int r = gw; r < rows; r += nw) {
        const float* wr = W + (size_t)r * K;
        float a0 = 0.f, a1 = 0.f, a2 = 0.f, a3 = 0.f;
        for (int k = l; k < K; k += 64) {
            float wv = wr[k];
            a0 += wv * in[k];
            a1 += wv * in[K + k];
            a2 += wv * in[2*K + k];
            a3 += wv * in[3*K + k];
        }
        #pragma unroll
        for (int off = 32; off; off >>= 1) {
            a0 += __shfl_xor(a0, off);
            a1 += __shfl_xor(a1, off);
            a2 += __shfl_xor(a2, off);
            a3 += __shfl_xor(a3, off);
        }
        if (l == 0) {
            float bb = bias[r];
            a0 += bb; a1 += bb; a2 += bb; a3 += bb;
            if (dorelu) {
                a0 = fmaxf(a0, 0.f); a1 = fmaxf(a1, 0.f);
                a2 = fmaxf(a2, 0.f); a3 = fmaxf(a3, 0.f);
            }
            if (ilv) {
                outp[r*4 + 0] = a0; outp[r*4 + 1] = a1;
                outp[r*4 + 2] = a2; outp[r*4 + 3] = a3;
            } else {
                outp[0*rows + r] = a0; outp[1*rows + r] = a1;
                outp[2*rows + r] = a2; outp[3*rows + r] = a3;
            }
        }
    }
}

extern "C" void kernel_launch(void* const* d_in, const int* in_sizes, int n_in,
                              void* d_out, int out_size, void* d_ws, size_t ws_size,
                              hipStream_t stream) {
    const float* xs = (const float*)d_in[0];
    const float* ts = (const float*)d_in[1];
    const float* A  = (const float*)d_in[2];
    const float* Bm = (const float*)d_in[3];
    const float* W1 = (const float*)d_in[4];
    const float* b1 = (const float*)d_in[5];
    const float* W2 = (const float*)d_in[6];
    const float* b2 = (const float*)d_in[7];
    const float* W3 = (const float*)d_in[8];
    const float* b3 = (const float*)d_in[9];
    // d_in[10] = seed: unused (FORCING_PROB == 1.0 makes the RNG dead code)
    float* outp = (float*)d_out;
    float* wsf  = (float*)d_ws;

    float* thetaA = wsf + OFF_THA;
    float* thetaB = wsf + OFF_THB;
    float* w1t    = wsf + OFF_W1T;
    float* w2t    = wsf + OFF_W2T;
    float* diffb  = wsf + OFF_DIFF;
    float* h1ws   = wsf + OFF_H1;
    float* h2ws   = wsf + OFF_H2;
    unsigned* ctr = (unsigned*)(wsf + OFF_CTR);

    init_h1<<<dim3((H1_DIM + 255)/256, B_SZ), 256, 0, stream>>>(xs, W1, b1, h1ws, diffb, ctr);
    init_mm<<<dim3(128), 256, 0, stream>>>(W2, b2, h1ws, h2ws, H2_DIM, H1_DIM, 1, 0);
    init_mm<<<dim3(256), 256, 0, stream>>>(W3, b3, h2ws, thetaA, L_DIM, H2_DIM, 0, 1);
    seq_kernel<<<dim3(NBLK), dim3(512), 0, stream>>>(A, Bm, xs, ts, outp,
                                                     thetaA, thetaB, w1t, w2t, diffb, ctr);
}

// Round 2
// 5041.052 us; speedup vs baseline: 1.8411x; 1.8411x over previous
//
#include <hip/hip_runtime.h>
#include <cmath>

#define T_STEPS 128
#define B_SZ    4
#define L_DIM   6368
#define L4V     1592      // A-row float4s
#define NCH     4
#define CH_SL   1592      // theta4 slots per chunk (k-dims per chunk)
#define CH_J    398       // A float4s per chunk = CH_SL/4 (398 = 6*64 + 14)
#define H1_DIM  2133
#define H2_DIM  4250
#define NBLK    256
#define NMV     255
#define NPAIR   3184      // L_DIM/2 row-pairs

// ws layout (float offsets)
#define OFF_THA  0
#define OFF_THB  25472
#define OFF_W1T  50944     // 2 slots * 16384
#define OFF_W2T  83712     // 2 slots * 8192
#define OFF_DIFF 100096    // 2 slots * 68
#define OFF_H1   100236    // 4*2133 scratch (init only)
#define OFF_H2   108768    // 4*4250 scratch (init only; ends 125768)
#define OFF_CTR  125824    // barrier: 17 slots * 32-u32 stride (zero 576 words)

typedef __attribute__((address_space(1))) void gvoid;
typedef __attribute__((address_space(3))) void lvoid;

__device__ __forceinline__ void fma4(float4& acc, float4 a, float4 t0, float4 t1, float4 t2, float4 t3) {
    acc.x += a.x*t0.x + a.y*t1.x + a.z*t2.x + a.w*t3.x;
    acc.y += a.x*t0.y + a.y*t1.y + a.z*t2.y + a.w*t3.y;
    acc.z += a.x*t0.z + a.y*t1.z + a.z*t2.z + a.w*t3.z;
    acc.w += a.x*t0.w + a.y*t1.w + a.z*t2.w + a.w*t3.w;
}

__device__ __forceinline__ float4 red4(float4 v) {
    #pragma unroll
    for (int off = 32; off; off >>= 1) {
        v.x += __shfl_xor(v.x, off);
        v.y += __shfl_xor(v.y, off);
        v.z += __shfl_xor(v.z, off);
        v.w += __shfl_xor(v.w, off);
    }
    return v;
}

// scatter w1/w2 regions of theta' transposed for the root MLP's coalesced reads
__device__ __forceinline__ void aux_write(float4* w1o, float4* w2o, int r, float4 v) {
    if (r >= 128 && r < 4224) {
        int j = r - 128;                   // j = r_mlp*64 + k
        w1o[(j & 63)*64 + (j >> 6)] = v;   // [k][r_mlp] x 4 batches
    } else if (r >= 4288 && r < 6336) {
        int j = r - 4288;
        w2o[(j & 63)*32 + (j >> 6)] = v;
    }
}

__device__ __forceinline__ float softplusf(float x) {
    return (x > 20.f) ? x : log1pf(expf(x));
}

// Grid barrier (256 blocks, 8 groups of 32). Arrival: relaxed agent RMW
// (executes at coherence point, never stale). Release: relaxed agent stores of
// it1 to 8 replicated flag lines. Poll: relaxed agent LOAD (sc1: bypasses
// L1/L2, sees remote stores; no write traffic, no per-poll buffer_inv).
// Data coherence: one release fence before arrival, one acquire fence after wake.
__device__ __forceinline__ void grid_barrier(unsigned* ctr, int myc, unsigned it1) {
    __syncthreads();   // all waves drain vmem before signaling
    if (threadIdx.x == 0) {
        __threadfence();  // release: write back theta'/w1t/w2t/diff stores
        unsigned old = __hip_atomic_fetch_add(&ctr[myc*32], 1u,
                           __ATOMIC_RELAXED, __HIP_MEMORY_SCOPE_AGENT);
        if (old == it1*32u - 1u) {          // last arriver of my group of 32
            unsigned o2 = __hip_atomic_fetch_add(&ctr[8*32], 1u,
                              __ATOMIC_RELAXED, __HIP_MEMORY_SCOPE_AGENT);
            if (o2 == it1*8u - 1u) {        // last group: release everyone
                #pragma unroll
                for (int c2 = 0; c2 < 8; ++c2)
                    __hip_atomic_store(&ctr[(9 + c2)*32], it1,
                        __ATOMIC_RELAXED, __HIP_MEMORY_SCOPE_AGENT);
            }
        }
        while (__hip_atomic_load(&ctr[(9 + myc)*32],
                   __ATOMIC_RELAXED, __HIP_MEMORY_SCOPE_AGENT) < it1)
            __builtin_amdgcn_s_sleep(8);
        __threadfence();  // acquire: invalidate caches before reading others' writes
    }
    __syncthreads();
}

// Stage one chunk (1592 float4) of theta into LDS, swizzled. LDS dest is
// LINEAR (global_load_lds: wave-uniform base + lane*16); the swizzle is applied
// to the GLOBAL source index (involution p ^ ((p>>3)&7)), so reads can use the
// same XOR. 3 full wave-instructions per wave + 7-lane tail via register.
__device__ __forceinline__ void stage_issue(const float4* __restrict__ src, float4* dst,
                                            int w, int l, float4& tailv) {
    #pragma unroll
    for (int k = 0; k < 3; ++k) {
        const int p = k*512 + w*64 + l;
        const int q = p ^ ((p >> 3) & 7);
        __builtin_amdgcn_global_load_lds((gvoid*)(src + q),
                                         (lvoid*)(dst + k*512 + w*64), 16, 0, 0);
    }
    const int p = 1536 + w*7 + l;
    if (l < 7) tailv = src[p ^ ((p >> 3) & 7)];   // vmcnt drains at the late ds_write
}

__device__ __forceinline__ void stage_tail(float4* dst, int w, int l, float4 tailv) {
    if (l < 7) dst[1536 + w*7 + l] = tailv;
}

// FMA over one chunk: rows rA,rA+1 (and rB,rB+1 if HB). Fully unrolled
// 6 trips + 14-lane tail; 4 swizzled ds_read_b128 feed 2 or 4 fma4 rows.
template<bool HB>
__device__ __forceinline__ void chunk_fma(const float4* __restrict__ a0, const float4* __restrict__ a1,
                                          const float4* __restrict__ c0, const float4* __restrict__ c1,
                                          const float4* __restrict__ sbuf, int jg0, int l,
                                          float4& A0, float4& A1, float4& B0, float4& B1)
{
    #pragma unroll
    for (int m = 0; m < 6; ++m) {
        const int jj = m*64 + l;
        const int jg = jg0 + jj;
        float4 av0 = a0[jg], av1 = a1[jg];
        float4 bv0, bv1;
        if (HB) { bv0 = c0[jg]; bv1 = c1[jg]; }
        const int sw = (jj >> 1) & 7;
        float4 t0 = sbuf[(4*jj + 0) ^ sw];
        float4 t1 = sbuf[(4*jj + 1) ^ sw];
        float4 t2 = sbuf[(4*jj + 2) ^ sw];
        float4 t3 = sbuf[(4*jj + 3) ^ sw];
        fma4(A0, av0, t0, t1, t2, t3);
        fma4(A1, av1, t0, t1, t2, t3);
        if (HB) {
            fma4(B0, bv0, t0, t1, t2, t3);
            fma4(B1, bv1, t0, t1, t2, t3);
        }
    }
    if (l < 14) {        // 398 = 6*64 + 14
        const int jj = 384 + l;
        const int jg = jg0 + jj;
        float4 av0 = a0[jg], av1 = a1[jg];
        float4 bv0, bv1;
        if (HB) { bv0 = c0[jg]; bv1 = c1[jg]; }
        const int sw = (jj >> 1) & 7;
        float4 t0 = sbuf[(4*jj + 0) ^ sw];
        float4 t1 = sbuf[(4*jj + 1) ^ sw];
        float4 t2 = sbuf[(4*jj + 2) ^ sw];
        float4 t3 = sbuf[(4*jj + 3) ^ sw];
        fma4(A0, av0, t0, t1, t2, t3);
        fma4(A1, av1, t0, t1, t2, t3);
        if (HB) {
            fma4(B0, bv0, t0, t1, t2, t3);
            fma4(B1, bv1, t0, t1, t2, t3);
        }
    }
}

__global__ __launch_bounds__(512, 2)   // 256-VGPR budget for deep load pipelining
void seq_kernel(const float* __restrict__ A,
                const float* __restrict__ Bm,
                const float* __restrict__ xs,
                const float* __restrict__ ts,
                float* __restrict__ outp,
                float* thetaA, float* thetaB,
                float* w1t, float* w2t, float* diffb,
                unsigned* ctr)
{
    __shared__ float4 sth[2*CH_SL];     // 50944 B double-buffered chunk
    const int blk = blockIdx.x;
    const int tid = threadIdx.x;
    const int w = tid >> 6, l = tid & 63;
    const int myc = blk & 7;
    const float4* A4 = (const float4*)A;

    if (blk < NMV) {
        // --------- matvec blocks: 2 row-pairs per wave (waves 0..k have pair B) ---------
        const int p0 = (blk * NPAIR) / NMV;
        const int p1 = ((blk + 1) * NPAIR) / NMV;   // 12..13 pairs per block
        const int pA = p0 + w;                       // always < p1
        const int pB = pA + 8;
        const bool hasB = pB < p1;
        const int rA = pA * 2;
        const int rB = pB * 2;
        const float4* a0 = A4 + (size_t)rA * L4V;
        const float4* a1 = a0 + L4V;
        const float4* c0 = A4 + (size_t)rB * L4V;
        const float4* c1 = c0 + L4V;

        // Bm rows preloaded once (rows are kernel-invariant)
        float bmA0 = 0.f, bmA1 = 0.f, bmB0 = 0.f, bmB1 = 0.f;
        if (l < 17) {
            bmA0 = Bm[rA*17 + l];
            bmA1 = Bm[(rA + 1)*17 + l];
            if (hasB) { bmB0 = Bm[rB*17 + l]; bmB1 = Bm[(rB + 1)*17 + l]; }
        }

        for (int it = 0; it < T_STEPS; ++it) {
            const float4* thIn4 = (const float4*)((it & 1) ? thetaB : thetaA);
            float4* thOut4 = (float4*)((it & 1) ? thetaA : thetaB);
            float4* w1o = (float4*)(w1t + ((it + 1) & 1) * 16384);
            float4* w2o = (float4*)(w2t + ((it + 1) & 1) * 8192);
            const float* dvec = diffb + (it & 1) * 68;

            float e0 = 0.f, e1 = 0.f, e2 = 0.f, e3 = 0.f;
            if (l < 17) { e0 = dvec[l]; e1 = dvec[17 + l]; e2 = dvec[34 + l]; e3 = dvec[51 + l]; }
            float4 A0 = make_float4(bmA0*e0, bmA0*e1, bmA0*e2, bmA0*e3);
            float4 A1 = make_float4(bmA1*e0, bmA1*e1, bmA1*e2, bmA1*e3);
            float4 B0 = make_float4(bmB0*e0, bmB0*e1, bmB0*e2, bmB0*e3);
            float4 B1 = make_float4(bmB1*e0, bmB1*e1, bmB1*e2, bmB1*e3);

            float4 tailv;
            // prologue: stage chunk 0
            stage_issue(thIn4, sth, w, l, tailv);
            stage_tail(sth, w, l, tailv);
            __syncthreads();                      // drains global_load_lds (vmcnt0) + ds_write

            for (int c = 0; c < NCH; ++c) {
                if (c + 1 < NCH)                  // async-stage next chunk into other buffer
                    stage_issue(thIn4 + (c + 1)*CH_SL, sth + ((c + 1) & 1)*CH_SL, w, l, tailv);
                const float4* sbuf = sth + (c & 1)*CH_SL;
                if (hasB) chunk_fma<true >(a0, a1, c0, c1, sbuf, c*CH_J, l, A0, A1, B0, B1);
                else      chunk_fma<false>(a0, a1, c0, c1, sbuf, c*CH_J, l, A0, A1, B0, B1);
                if (c + 1 < NCH) {
                    stage_tail(sth + ((c + 1) & 1)*CH_SL, w, l, tailv);
                    __syncthreads();              // stage(c+1) landed; readers of buf done
                }
            }

            A0 = red4(A0); A1 = red4(A1);
            if (hasB) { B0 = red4(B0); B1 = red4(B1); }
            if (l == 0) {
                thOut4[rA]     = A0;  aux_write(w1o, w2o, rA,     A0);
                thOut4[rA + 1] = A1;  aux_write(w1o, w2o, rA + 1, A1);
                if (hasB) {
                    thOut4[rB]     = B0;  aux_write(w1o, w2o, rB,     B0);
                    thOut4[rB + 1] = B1;  aux_write(w1o, w2o, rB + 1, B1);
                }
            }
            grid_barrier(ctr, myc, (unsigned)(it + 1));
        }
    } else {
        // --------- root block: root_apply_{it-1} + prepare diff_{it+1} ---------
        const int b = w;  // waves 0..3 = batches; 4..7 idle
        for (int it = 0; it <= T_STEPS; ++it) {
            float xv = 0.f;
            if (b < B_SZ) {
                if (it >= 1) {
                    const int t = it - 1;
                    const float* th  = (it & 1) ? thetaB : thetaA;  // theta^{it}
                    const float* w1c = w1t + (it & 1) * 16384;
                    const float* w2c = w2t + (it & 1) * 8192;
                    float tcur = ts[b*T_STEPS + t];
                    float tin = (t >= 1) ? (2.f*tcur - ts[b*T_STEPS + t - 1]) : tcur;
                    // h0 = relu(w0*tin + c0)
                    float h0 = fmaxf(th[l*4 + b] * tin + th[(64 + l)*4 + b], 0.f);
                    // h1 = relu(w1 @ h0 + c1)
                    float a1v = th[(4224 + l)*4 + b];
                    #pragma unroll
                    for (int k = 0; k < 64; ++k)
                        a1v += w1c[(k*64 + l)*4 + b] * __shfl(h0, k);
                    float h1 = fmaxf(a1v, 0.f);
                    // o = w2 @ h1 + c2  (32 outputs, lanes 0..31)
                    float ov = th[(6336 + (l & 31))*4 + b];
                    #pragma unroll
                    for (int k = 0; k < 64; ++k)
                        ov += w2c[(k*32 + (l & 31))*4 + b] * __shfl(h1, k);
                    if (l < 32) {
                        xv = (l < 16) ? tanhf(ov) : softplusf(ov);
                        outp[(b*T_STEPS + t)*32 + l] = xv;
                    }
                }
                if (it + 1 <= T_STEPS - 1) {
                    float* dd = diffb + ((it + 1) & 1) * 68 + b*17;
                    if (l < 16) {
                        float xprev = (it >= 1) ? xv : xs[(size_t)(b*T_STEPS)*16 + l];
                        dd[1 + l] = xs[(size_t)(b*T_STEPS + it + 1)*16 + l] - xprev;
                    } else if (l == 16) {
                        dd[0] = ts[b*T_STEPS + it + 1] - ts[b*T_STEPS + it];
                    }
                }
            }
            if (it < T_STEPS) grid_barrier(ctr, myc, (unsigned)(it + 1));
        }
    }
}

// h1 = relu(W1 @ xs0 + b1), plus zero diff slots and barrier counters
__global__ __launch_bounds__(256)
void init_h1(const float* __restrict__ xs, const float* __restrict__ W1,
             const float* __restrict__ b1, float* __restrict__ h1ws,
             float* __restrict__ diffb, unsigned* __restrict__ ctr)
{
    const int b = blockIdx.y;
    const int r = blockIdx.x * 256 + threadIdx.x;
    if (blockIdx.x == 0 && b == 0) {
        if (threadIdx.x < 136) diffb[threadIdx.x] = 0.f;
        for (int z = threadIdx.x; z < 576; z += 256) ctr[z] = 0u;
    }
    if (r < H1_DIM) {
        const float* wr = W1 + r*16;
        const float* x0 = xs + (size_t)b * T_STEPS * 16;
        float s = b1[r];
        #pragma unroll
        for (int k = 0; k < 16; ++k) s += wr[k] * x0[k];
        h1ws[b*H1_DIM + r] = fmaxf(s, 0.f);
    }
}

// out[b][r] = maybe_relu(sum_k W[r][k]*in[b][k] + bias[r]); ilv => out[r*4+b]
__global__ __launch_bounds__(256)
void init_mm(const float* __restrict__ W, const float* __restrict__ bias,
             const float* __restrict__ in, float* __restrict__ outp,
             int rows, int K, int dorelu, int ilv)
{
    const int w = threadIdx.x >> 6, l = threadIdx.x & 63;
    const int gw = blockIdx.x * 4 + w;
    const int nw = gridDim.x * 4;
    for (int r = gw; r < rows; r += nw) {
        const float* wr = W + (size_t)r * K;
        float a0 = 0.f, a1 = 0.f, a2 = 0.f, a3 = 0.f;
        for (int k = l; k < K; k += 64) {
            float wv = wr[k];
            a0 += wv * in[k];
            a1 += wv * in[K + k];
            a2 += wv * in[2*K + k];
            a3 += wv * in[3*K + k];
        }
        #pragma unroll
        for (int off = 32; off; off >>= 1) {
            a0 += __shfl_xor(a0, off);
            a1 += __shfl_xor(a1, off);
            a2 += __shfl_xor(a2, off);
            a3 += __shfl_xor(a3, off);
        }
        if (l == 0) {
            float bb = bias[r];
            a0 += bb; a1 += bb; a2 += bb; a3 += bb;
            if (dorelu) {
                a0 = fmaxf(a0, 0.f); a1 = fmaxf(a1, 0.f);
                a2 = fmaxf(a2, 0.f); a3 = fmaxf(a3, 0.f);
            }
            if (ilv) {
                outp[r*4 + 0] = a0; outp[r*4 + 1] = a1;
                outp[r*4 + 2] = a2; outp[r*4 + 3] = a3;
            } else {
                outp[0*rows + r] = a0; outp[1*rows + r] = a1;
                outp[2*rows + r] = a2; outp[3*rows + r] = a3;
            }
        }
    }
}

extern "C" void kernel_launch(void* const* d_in, const int* in_sizes, int n_in,
                              void* d_out, int out_size, void* d_ws, size_t ws_size,
                              hipStream_t stream) {
    const float* xs = (const float*)d_in[0];
    const float* ts = (const float*)d_in[1];
    const float* A  = (const float*)d_in[2];
    const float* Bm = (const float*)d_in[3];
    const float* W1 = (const float*)d_in[4];
    const float* b1 = (const float*)d_in[5];
    const float* W2 = (const float*)d_in[6];
    const float* b2 = (const float*)d_in[7];
    const float* W3 = (const float*)d_in[8];
    const float* b3 = (const float*)d_in[9];
    // d_in[10] = seed: unused (FORCING_PROB == 1.0 makes the RNG dead code)
    float* outp = (float*)d_out;
    float* wsf  = (float*)d_ws;

    float* thetaA = wsf + OFF_THA;
    float* thetaB = wsf + OFF_THB;
    float* w1t    = wsf + OFF_W1T;
    float* w2t    = wsf + OFF_W2T;
    float* diffb  = wsf + OFF_DIFF;
    float* h1ws   = wsf + OFF_H1;
    float* h2ws   = wsf + OFF_H2;
    unsigned* ctr = (unsigned*)(wsf + OFF_CTR);

    init_h1<<<dim3((H1_DIM + 255)/256, B_SZ), 256, 0, stream>>>(xs, W1, b1, h1ws, diffb, ctr);
    init_mm<<<dim3(128), 256, 0, stream>>>(W2, b2, h1ws, h2ws, H2_DIM, H1_DIM, 1, 0);
    init_mm<<<dim3(256), 256, 0, stream>>>(W3, b3, h2ws, thetaA, L_DIM, H2_DIM, 0, 1);
    seq_kernel<<<dim3(NBLK), dim3(512), 0, stream>>>(A, Bm, xs, ts, outp,
                                                     thetaA, thetaB, w1t, w2t, diffb, ctr);
}